// Round 13
// baseline (307.896 us; speedup 1.0000x reference)
//
#include <hip/hip_runtime.h>
#include <hip/hip_bf16.h>
#include <math.h>

// ConvNeXt MLP + parallel MoE-LoRA, fp32 in/out, bf16-tolerance harness.
// B,H,W,C = 64,14,14,768 ; N_tok = 12544 = 98*128 ; HID = 3072 ; E=8,K=2,R=16.
//
//   h  = gelu(x @ w1 + b1)          \  GEMM1m [12544,768]x[768,3072] (TM=256)
//   sd = wt * gelu(x @ wdown)       /  + 49 folded LoRA blocks (TN=128 = all R*E)
//   out = [h | sd] @ [w2 ; wup] + b2   GEMM2  [12544,3200]x[3200,768]
//
// R13 = R12 + GEMMd folded into GEMM1 as tail y-rows. R4-R7's fold failed for
//   two specific reasons, both fixed here: (a) grid width must stay = 0 mod 8
//   (width 24 kept; tail rows remap block-uniformly); (b) VGPR inflation
//   84->108 killed occupancy — TM=256 GEMM1 is at 52 VGPR, ample headroom.
//   Eliminates the separate GEMMd dispatch (~25-30 us of 60%-idle GPU).
//   GEMM2 (TM=128, 624-block XCD swizzle) and prep frozen.

#define NTOK   12544
#define CDIM   768
#define HIDDIM 3072
#define KBIG   3200

typedef __attribute__((ext_vector_type(8))) short bf16x8;
typedef __attribute__((ext_vector_type(4))) float f32x4;

#define GLOBAL_AS(p) ((const __attribute__((address_space(1))) void*)(p))
#define LDS_AS(p)    ((__attribute__((address_space(3))) void*)(p))

__device__ inline unsigned short f2bf(float f) {
    unsigned int x = __float_as_uint(f);
    x += 0x7fffu + ((x >> 16) & 1u);   // RNE
    return (unsigned short)(x >> 16);
}

// tanh-form GELU, branch-free; max |err| ~4.3e-4 vs exact erf form.
__device__ inline float gelu_fast(float x) {
    float x3 = x * x * x;
    float u2 = 1.5957691216057308f * x + 0.07135481627260025f * x3;
    float e = __expf(-u2);
    return x * __builtin_amdgcn_rcpf(1.0f + e);
}

// ---------------- fused prep: cast_x + 3 transposes (64x64) + pack_wdown -------
__global__ void __launch_bounds__(256) prep_kernel(
        const float* __restrict__ x, const float* __restrict__ w1,
        const float* __restrict__ w2, const float* __restrict__ wup,
        const float* __restrict__ wdn,
        unsigned short* __restrict__ xb, unsigned short* __restrict__ w1t,
        unsigned short* __restrict__ B2t, unsigned short* __restrict__ wdt) {
    __shared__ float tile[64][65];
    const int b = blockIdx.x, tid = threadIdx.x;
    if (b < 9408) {                      // cast x -> bf16, float4->ushort4
        int i = b * 256 + tid;
        float4 v = ((const float4*)x)[i];
        ushort4 o;
        o.x = f2bf(v.x); o.y = f2bf(v.y); o.z = f2bf(v.z); o.w = f2bf(v.w);
        ((ushort4*)xb)[i] = o;
        return;
    }
    if (b < 10584) {                     // 64x64 transpose tiles
        const float* in; unsigned short* outp; int Ccols, out_ld, out_off, bx, by;
        if (b < 9984)       { int t = b - 9408;  in = w1;  outp = w1t; Ccols = 3072; out_ld = 768;  out_off = 0;    bx = t % 48; by = t / 48; }
        else if (b < 10560) { int t = b - 9984;  in = w2;  outp = B2t; Ccols = 768;  out_ld = 3200; out_off = 0;    bx = t % 12; by = t / 12; }
        else                { int t = b - 10560; in = wup; outp = B2t; Ccols = 768;  out_ld = 3200; out_off = 3072; bx = t % 12; by = t / 12; }
        const int c0 = bx * 64, r0 = by * 64;
        #pragma unroll
        for (int p = 0; p < 4; ++p) {
            int idx = p * 256 + tid;
            int r = idx >> 4, c4 = (idx & 15) * 4;
            float4 v = *(const float4*)&in[(size_t)(r0 + r) * Ccols + c0 + c4];
            tile[r][c4 + 0] = v.x; tile[r][c4 + 1] = v.y;
            tile[r][c4 + 2] = v.z; tile[r][c4 + 3] = v.w;
        }
        __syncthreads();
        #pragma unroll
        for (int p = 0; p < 2; ++p) {
            int u = p * 256 + tid;
            int cc = u >> 3, r8 = (u & 7) * 8;
            uint4 pk;
            pk.x = (unsigned)f2bf(tile[r8 + 0][cc]) | ((unsigned)f2bf(tile[r8 + 1][cc]) << 16);
            pk.y = (unsigned)f2bf(tile[r8 + 2][cc]) | ((unsigned)f2bf(tile[r8 + 3][cc]) << 16);
            pk.z = (unsigned)f2bf(tile[r8 + 4][cc]) | ((unsigned)f2bf(tile[r8 + 5][cc]) << 16);
            pk.w = (unsigned)f2bf(tile[r8 + 6][cc]) | ((unsigned)f2bf(tile[r8 + 7][cc]) << 16);
            *(uint4*)&outp[(size_t)(c0 + cc) * out_ld + out_off + r0 + r8] = pk;
        }
        return;
    }
    {   // pack_wdown: wdt[j][c] = wdown[e][c][r], j = e*16+r
        int idx = (b - 10584) * 256 + tid;
        int j = idx / 768, c = idx - j * 768;
        int e = j >> 4, r = j & 15;
        wdt[idx] = f2bf(wdn[((size_t)e * 768 + c) * 16 + r]);
    }
}

// ---- MFMA GEMM, C = A * Bt^T, TM x 128 tile, BK=32, LDS double-buffer --------
// EPI 3 (TM=256, grid 24x52): by<49 -> h-tile: gelu(acc+b1) -> bf16 Ap[:, n].
//   by>=49 -> block-uniform remap to 49 LoRA blocks: B=wdt, n0=0,
//   wt[m,e]*gelu(acc) -> bf16 Ap[:, 3072+n].
// EPI 2 (TM=128, 1-D XCD-swizzled grid): acc + b2[n] -> f32 out.

template <int EPI, int TM>
__global__ void __launch_bounds__(TM * 2)
gemm_bt_kernel(const unsigned short* __restrict__ A, int lda,
               const unsigned short* __restrict__ Bt, int ldb,
               const unsigned short* __restrict__ Bt2,   // LoRA B (EPI3)
               int kIters,
               const float* __restrict__ bias,
               unsigned short* __restrict__ apOut,
               float* __restrict__ fOut,
               const int* __restrict__ tki,
               const float* __restrict__ tkp) {
    constexpr int NT    = TM * 2;          // threads
    constexpr int ABUF  = TM * 32;         // elems per A buffer
    constexpr int BBUF  = 128 * 32;        // elems per B buffer
    __shared__ __align__(16) unsigned short As[2 * ABUF];
    __shared__ __align__(16) unsigned short Bs[2 * BBUF];

    int bx, by;
    bool lora = false;
    if (EPI == 2) {
        // 624 blocks; same-m-row blocks share L&7 -> same XCD, consecutive.
        int L = blockIdx.x;
        int k = L & 7, t = L >> 3;
        bx = t % 6;
        by = (t / 6) * 8 + k;
        if (by >= NTOK / 128) return;      // block-uniform, pre-barrier safe
    } else {
        bx = blockIdx.x;
        by = blockIdx.y;
        if (by >= 49) {                    // tail rows -> 49 LoRA blocks
            int lby = (by - 49) * 24 + bx;
            if (lby >= 49) return;         // block-uniform, pre-barrier safe
            by = lby; lora = true;
        }
    }

    const unsigned short* BtP = (EPI == 3 && lora) ? Bt2 : Bt;

    const int tid  = threadIdx.x;
    const int wave = tid >> 6;
    const int lane = tid & 63;
    const int m0 = by * TM;
    const int n0 = (EPI == 3 && lora) ? 0 : bx * 128;
    const int wm = (wave >> 1) * 64;
    const int wn = (wave & 1) * 64;
    const int row16 = lane & 15;
    const int quad  = lane >> 4;
    const int kch   = quad * 8;

    f32x4 acc[4][4] = {};

    // Staging (proven layout): chunk ci covers a [rows][32] tile row-major
    // (row = ci>>2, kcol = (ci&3)*8); source contiguous in lane order; LDS
    // dest = wave-uniform base + lane*16B. 64-B row stride (2-bank, free).
    const int r_s = tid >> 2;
    const int c_s = (tid & 3) * 8;
    const size_t aRow0 = (size_t)(m0 + r_s) * lda + c_s;
    const size_t aRow1 = aRow0 + (size_t)(NT / 4) * lda;
    const size_t bRow0 = (size_t)(n0 + r_s) * ldb + c_s;
    const size_t bRow1 = bRow0 + (size_t)64 * ldb;       // used only if TM==128
    unsigned short* asB0 = &As[(wave * 64) * 8];
    unsigned short* asB1 = &As[(NT + wave * 64) * 8];
    unsigned short* bsB0 = &Bs[(wave * 64) * 8];
    unsigned short* bsB1 = &Bs[(256 + wave * 64) * 8];

    // prologue: prefetch tile 0 into buffer 0
    {
        __builtin_amdgcn_global_load_lds(GLOBAL_AS(A + aRow0), LDS_AS(asB0), 16, 0, 0);
        __builtin_amdgcn_global_load_lds(GLOBAL_AS(A + aRow1), LDS_AS(asB1), 16, 0, 0);
        __builtin_amdgcn_global_load_lds(GLOBAL_AS(BtP + bRow0), LDS_AS(bsB0), 16, 0, 0);
        if (TM == 128)
            __builtin_amdgcn_global_load_lds(GLOBAL_AS(BtP + bRow1), LDS_AS(bsB1), 16, 0, 0);
    }

    for (int kt = 0; kt < kIters; ++kt) {
        // barrier: compiler-emitted vmcnt(0)+lgkmcnt(0) drain guarantees
        // buf[kt&1] landed AND all waves done reading buf[(kt+1)&1].
        __syncthreads();

        if (kt + 1 < kIters) {             // prefetch kt+1 into alternate buffer
            const int k1 = (kt + 1) * 32;
            const int pa = ((kt + 1) & 1) * ABUF;
            const int pb = ((kt + 1) & 1) * BBUF;
            __builtin_amdgcn_global_load_lds(GLOBAL_AS(A + aRow0 + k1), LDS_AS(asB0 + pa), 16, 0, 0);
            __builtin_amdgcn_global_load_lds(GLOBAL_AS(A + aRow1 + k1), LDS_AS(asB1 + pa), 16, 0, 0);
            __builtin_amdgcn_global_load_lds(GLOBAL_AS(BtP + bRow0 + k1), LDS_AS(bsB0 + pb), 16, 0, 0);
            if (TM == 128)
                __builtin_amdgcn_global_load_lds(GLOBAL_AS(BtP + bRow1 + k1), LDS_AS(bsB1 + pb), 16, 0, 0);
        }

        const int ca = (kt & 1) * ABUF;
        const int cb = (kt & 1) * BBUF;
        bf16x8 af[4], bfr[4];
        #pragma unroll
        for (int mi = 0; mi < 4; ++mi)
            af[mi] = *(const bf16x8*)&As[ca + (wm + mi * 16 + row16) * 32 + kch];
        #pragma unroll
        for (int ni = 0; ni < 4; ++ni)
            bfr[ni] = *(const bf16x8*)&Bs[cb + (wn + ni * 16 + row16) * 32 + kch];

        #pragma unroll
        for (int mi = 0; mi < 4; ++mi)
            #pragma unroll
            for (int ni = 0; ni < 4; ++ni)
                acc[mi][ni] = __builtin_amdgcn_mfma_f32_16x16x32_bf16(
                    af[mi], bfr[ni], acc[mi][ni], 0, 0, 0);
    }

    // epilogue (R8-exact layout): lane holds col = row16 (+16*ni),
    // rows quad*4 + i. `lora` is block-uniform — no lane divergence.
    #pragma unroll
    for (int mi = 0; mi < 4; ++mi) {
        #pragma unroll
        for (int i = 0; i < 4; ++i) {
            const int m = m0 + wm + mi * 16 + quad * 4 + i;
            int i0 = 0, i1 = 0; float p0 = 0.f, p1 = 0.f;
            if (EPI == 3 && lora) {
                i0 = tki[m * 2]; i1 = tki[m * 2 + 1];
                p0 = tkp[m * 2]; p1 = tkp[m * 2 + 1];
            }
            #pragma unroll
            for (int ni = 0; ni < 4; ++ni) {
                const int ncol = n0 + wn + ni * 16 + row16;
                float v = acc[mi][ni][i];
                if (EPI == 3) {
                    if (lora) {
                        const int e = ncol >> 4;   // n0==0, ncol in [0,128)
                        float wt = (i0 == e ? p0 : 0.f) + (i1 == e ? p1 : 0.f);
                        v = gelu_fast(v) * wt;
                        apOut[(size_t)m * KBIG + 3072 + ncol] = f2bf(v);
                    } else {
                        v = gelu_fast(v + bias[ncol]);
                        apOut[(size_t)m * KBIG + ncol] = f2bf(v);
                    }
                } else {
                    fOut[(size_t)m * CDIM + ncol] = v + bias[ncol];
                }
            }
        }
    }
}

// ---------------- launch ----------------

extern "C" void kernel_launch(void* const* d_in, const int* in_sizes, int n_in,
                              void* d_out, int out_size, void* d_ws, size_t ws_size,
                              hipStream_t stream) {
    const float* x   = (const float*)d_in[0];
    const float* tkp = (const float*)d_in[1];
    const int*   tki = (const int*)d_in[2];
    const float* w1  = (const float*)d_in[3];
    const float* b1  = (const float*)d_in[4];
    const float* w2  = (const float*)d_in[5];
    const float* b2  = (const float*)d_in[6];
    const float* wdn = (const float*)d_in[7];
    const float* wup = (const float*)d_in[8];
    float* out = (float*)d_out;

    unsigned short* xb  = (unsigned short*)d_ws;
    unsigned short* w1t = xb  + (size_t)NTOK * CDIM;      // 3072 x 768
    unsigned short* B2t = w1t + (size_t)HIDDIM * CDIM;    // 768 x 3200
    unsigned short* wdt = B2t + (size_t)CDIM * KBIG;      // 128 x 768
    unsigned short* Ap  = wdt + (size_t)128 * CDIM;       // 12544 x 3200

    prep_kernel<<<dim3(10968), 256, 0, stream>>>(x, w1, w2, wup, wdn,
                                                 xb, w1t, B2t, wdt);

    // GEMM1 merged (+49 LoRA blocks): TM=256, grid (24, 52), 512 threads.
    // Width 24 (mod-8 XCD alignment) preserved; tail rows remap to LoRA.
    gemm_bt_kernel<3, 256><<<dim3(24, 52), 512, 0, stream>>>(
        xb, CDIM, w1t, CDIM, wdt, CDIM / 32, b1, Ap, nullptr, tki, tkp);

    // GEMM2: out = Ap @ B2t^T + b2 ; 624-block XCD-swizzled grid, TM=128
    gemm_bt_kernel<2, 128><<<dim3(624), 256, 0, stream>>>(
        Ap, KBIG, B2t, KBIG, nullptr, KBIG / 32, b2, nullptr, out, nullptr, nullptr);
}